// Round 5
// baseline (115.977 us; speedup 1.0000x reference)
//
#include <hip/hip_runtime.h>

#define NCELLS (8192 * 7 * 7)       // 401408 = 1568 * 256 exactly
#define BLOCK 256
#define NBLK (NCELLS / BLOCK)       // 1568
#define F4PB (BLOCK * 30 / 4)       // float4s per block per array = 1920

__device__ __forceinline__ float sq(float x) { return x * x; }

__device__ __forceinline__ float iou_fn(const float* t, const float* p, float fi, float fj) {
    const float STEP = 1.0f / 7.0f;
    float w1 = t[2], h1 = t[3];
    float x1 = (t[0] + fj) * STEP, y1 = (t[1] + fi) * STEP;
    float a1 = fmaxf(x1 - w1 * 0.5f, 0.0f);
    float b1 = fmaxf(y1 - h1 * 0.5f, 0.0f);
    float w2 = p[2], h2 = p[3];
    float x2 = (p[0] + fj) * STEP, y2 = (p[1] + fi) * STEP;
    float a2 = fmaxf(x2 - w2 * 0.5f, 0.0f);
    float b2 = fmaxf(y2 - h2 * 0.5f, 0.0f);
    float iw = w1 + w2 - (fmaxf(a1 + w1, a2 + w2) - fminf(a1, a2));
    float ih = h1 + h2 - (fmaxf(b1 + h1, b2 + h2) - fminf(b1, b2));
    bool valid = (iw > 0.0f) && (ih > 0.0f);
    float inter = valid ? iw * ih : 0.0f;
    float uni = w1 * h1 + w2 * h2 - inter;
    return valid ? inter / uni : 0.0f;
}

// Pass 1: coalesced float4 global->LDS staging, per-cell compute from LDS,
// block reduce, ONE plain float4 store per block (own slot -> no atomics,
// no zero-init, no memset dispatch).
__global__ __launch_bounds__(BLOCK) void yolo_part_kernel(
        const float4* __restrict__ pred4, const float4* __restrict__ tgt4,
        float4* __restrict__ partials) {
    __shared__ float4 sp4[F4PB];
    __shared__ float4 st4[F4PB];
    const float* sp = (const float*)sp4;
    const float* st = (const float*)st4;

    const int tid = threadIdx.x;
    const size_t base4 = (size_t)blockIdx.x * F4PB;

    // 1920 = 7.5 * 256 lane-consecutive float4s per array.
#pragma unroll
    for (int i = 0; i < 8; ++i) {
        int k = i * BLOCK + tid;
        if (i < 7 || tid < 128) {
            sp4[k] = pred4[base4 + k];
            st4[k] = tgt4[base4 + k];
        }
    }
    __syncthreads();

    const float invB = 1.0f / 8192.0f;
    int cg = blockIdx.x * BLOCK + tid;          // global cell index
    unsigned cell = (unsigned)cg % 49u;
    float fi = (float)(cell / 7u);
    float fj = (float)(cell % 7u);

    const float* p = sp + tid * 30;
    const float* t = st + tid * 30;

    float pl[30], tl[30];
#pragma unroll
    for (int k = 0; k < 30; ++k) { pl[k] = p[k]; tl[k] = t[k]; }

    bool obj = tl[4] > 0.0f;                    // target[...,4] is exactly 1.0 or 0.0

    float iou1 = iou_fn(tl, pl, fi, fj);
    float iou2 = iou_fn(tl, pl + 5, fi, fj);
    bool choose1 = iou1 > iou2;
    float m1 = (obj && choose1 && (iou1 != 0.0f)) ? 1.0f : 0.0f;
    float m2 = (obj && !choose1 && (iou2 != 0.0f)) ? 1.0f : 0.0f;

    float obj_loss = m1 * sq(iou1 - pl[4]) + m2 * sq(iou2 - pl[9]);

    float xy = m1 * (sq(tl[0] - pl[0]) + sq(tl[1] - pl[1]))
             + m2 * (sq(tl[5] - pl[5]) + sq(tl[6] - pl[6]));

    float wh = m1 * (sq(sqrtf(tl[2]) - sqrtf(pl[2])) + sq(sqrtf(tl[3]) - sqrtf(pl[3])))
             + m2 * (sq(sqrtf(tl[7]) - sqrtf(pl[7])) + sq(sqrtf(tl[8]) - sqrtf(pl[8])));

    float noobj = 0.0f;
#pragma unroll
    for (int k = 0; k < 6; ++k) {
        int ci = 4 + 5 * k;                     // 4, 9, 14, 19, 24, 29
        noobj += sq(tl[ci] - pl[ci]);
    }
    if (obj) noobj = 0.0f;

    float clsum = 0.0f;
#pragma unroll
    for (int k = 10; k < 30; ++k) clsum += sq(pl[k] - tl[k]);
    if (!obj) clsum = 0.0f;

    float conf = (obj_loss + 0.5f * noobj) * invB;
    float reg  = 5.0f * (xy + wh) * invB;
    float cls  = clsum * invB;

#pragma unroll
    for (int off = 32; off > 0; off >>= 1) {
        conf += __shfl_down(conf, off, 64);
        reg  += __shfl_down(reg,  off, 64);
        cls  += __shfl_down(cls,  off, 64);
    }

    __shared__ float s[3][4];
    int lane = tid & 63;
    int wave = tid >> 6;
    if (lane == 0) { s[0][wave] = conf; s[1][wave] = reg; s[2][wave] = cls; }
    __syncthreads();
    if (tid == 0) {
        float4 v;
        v.x = s[0][0] + s[0][1] + s[0][2] + s[0][3];
        v.y = s[1][0] + s[1][1] + s[1][2] + s[1][3];
        v.z = s[2][0] + s[2][1] + s[2][2] + s[2][3];
        v.w = 0.0f;
        partials[blockIdx.x] = v;               // own slot: plain store
    }
}

// Pass 2: one block folds the 1568 slots and writes the 3 outputs.
__global__ __launch_bounds__(BLOCK) void yolo_final_kernel(
        const float4* __restrict__ partials, float* __restrict__ out) {
    int tid = threadIdx.x;
    float a = 0.0f, b = 0.0f, d = 0.0f;
    for (int i = tid; i < NBLK; i += BLOCK) {   // 1568 float4, coalesced
        float4 v = partials[i];
        a += v.x; b += v.y; d += v.z;
    }
#pragma unroll
    for (int off = 32; off > 0; off >>= 1) {
        a += __shfl_down(a, off, 64);
        b += __shfl_down(b, off, 64);
        d += __shfl_down(d, off, 64);
    }
    __shared__ float s[3][4];
    int lane = tid & 63;
    int wave = tid >> 6;
    if (lane == 0) { s[0][wave] = a; s[1][wave] = b; s[2][wave] = d; }
    __syncthreads();
    if (tid == 0) {
        out[0] = s[0][0] + s[0][1] + s[0][2] + s[0][3];
        out[1] = s[1][0] + s[1][1] + s[1][2] + s[1][3];
        out[2] = s[2][0] + s[2][1] + s[2][2] + s[2][3];
    }
}

extern "C" void kernel_launch(void* const* d_in, const int* in_sizes, int n_in,
                              void* d_out, int out_size, void* d_ws, size_t ws_size,
                              hipStream_t stream) {
    const float4* pred4 = (const float4*)d_in[0];
    const float4* tgt4  = (const float4*)d_in[1];
    float* out = (float*)d_out;
    float4* partials = (float4*)d_ws;           // NBLK * 16 B = 25088 B

    yolo_part_kernel<<<NBLK, BLOCK, 0, stream>>>(pred4, tgt4, partials);
    yolo_final_kernel<<<1, BLOCK, 0, stream>>>(partials, out);
}